// Round 1
// baseline (97.788 us; speedup 1.0000x reference)
//
#include <hip/hip_runtime.h>
#include <math.h>

#define B_ 2
#define N_ 768
#define T_ 96
#define FM_ 8
#define HID_ 64
#define TD_ 32
#define MD_ 32
#define TILE 16
#define NTILES (N_/TILE)            // 48
#define NTP (NTILES*(NTILES+1)/2)   // 1176

__device__ __forceinline__ float wave_sum64(float v){
  #pragma unroll
  for (int m = 32; m; m >>= 1) v += __shfl_xor(v, m);
  return v;
}
__device__ __forceinline__ float wave_max64(float v){
  #pragma unroll
  for (int m = 32; m; m >>= 1) v = fmaxf(v, __shfl_xor(v, m));
  return v;
}

// ---------------------------------------------------------------------------
// Kernel 1: per-(b,n) features -> h, s_i, s_j   (1536 blocks x 64 threads)
// ---------------------------------------------------------------------------
__global__ __launch_bounds__(64) void feat_kernel(
    const float* __restrict__ x_hist, const float* __restrict__ x_mark,
    const float* __restrict__ te_w1, const float* __restrict__ te_b1,
    const float* __restrict__ te_w2, const float* __restrict__ te_b2,
    const float* __restrict__ me_w1, const float* __restrict__ me_b1,
    const float* __restrict__ me_w2, const float* __restrict__ me_b2,
    const float* __restrict__ nf_w,  const float* __restrict__ nf_b,
    const float* __restrict__ ps_w1,
    float* __restrict__ h_out, float* __restrict__ si_out, float* __restrict__ sj_out)
{
  const int row  = blockIdx.x;          // b*N + n
  const int lane = threadIdx.x;         // 0..63

  __shared__ float st[3];
  __shared__ float ms[FM_];
  __shared__ float t1s[TD_];
  __shared__ float m1s[MD_];
  __shared__ float hc[HID_];
  __shared__ float hs[HID_];

  // --- stats: last, mean, max over T=96 ---
  const float* xh = x_hist + (long)row * T_;
  float s  = xh[lane];
  float mx = s;
  if (lane < T_ - 64) { float v = xh[lane + 64]; s += v; mx = fmaxf(mx, v); }
  s  = wave_sum64(s);
  mx = wave_max64(mx);
  if (lane == 0) { st[0] = xh[T_ - 1]; st[1] = s * (1.0f / T_); st[2] = mx; }

  // --- mark mean over T: lane l handles f=l&7, t0=l>>3, t = t0+8k ---
  const float* xm = x_mark + (long)row * T_ * FM_;
  float msv = 0.f;
  #pragma unroll
  for (int k = 0; k < 12; ++k) msv += xm[lane + 64 * k];
  msv += __shfl_xor(msv, 8);
  msv += __shfl_xor(msv, 16);
  msv += __shfl_xor(msv, 32);
  if (lane < FM_) ms[lane] = msv * (1.0f / T_);
  __syncthreads();

  // --- time / mark encoder layer 1 (lanes 0..31) ---
  if (lane < TD_) {
    float a = te_b1[lane];
    #pragma unroll
    for (int k = 0; k < 3; ++k) a += st[k] * te_w1[k * TD_ + lane];
    t1s[lane] = fmaxf(a, 0.f);
    float am = me_b1[lane];
    #pragma unroll
    for (int k = 0; k < FM_; ++k) am += ms[k] * me_w1[k * MD_ + lane];
    m1s[lane] = fmaxf(am, 0.f);
  }
  __syncthreads();
  // --- layer 2 -> hc = concat(h_t, h_m) ---
  if (lane < TD_) {
    float a = te_b2[lane];
    #pragma unroll
    for (int k = 0; k < TD_; ++k) a += t1s[k] * te_w2[k * TD_ + lane];
    hc[lane] = a;
    float am = me_b2[lane];
    #pragma unroll
    for (int k = 0; k < MD_; ++k) am += m1s[k] * me_w2[k * MD_ + lane];
    hc[TD_ + lane] = am;
  }
  __syncthreads();
  // --- node fuse: h = relu(hc @ nf_w + nf_b) ---
  {
    float a = nf_b[lane];
    #pragma unroll
    for (int k = 0; k < HID_; ++k) a += hc[k] * nf_w[k * HID_ + lane];
    float hv = fmaxf(a, 0.f);
    hs[lane] = hv;
    h_out[(long)row * HID_ + lane] = hv;
  }
  __syncthreads();
  // --- s_i = h @ w_i, s_j = h @ w_j  (ps_w1 rows [0,64) and [64,128)) ---
  {
    float a1 = 0.f, a2 = 0.f;
    #pragma unroll
    for (int k = 0; k < HID_; ++k) {
      float hv = hs[k];
      a1 += hv * ps_w1[k * HID_ + lane];
      a2 += hv * ps_w1[(HID_ + k) * HID_ + lane];
    }
    si_out[(long)row * HID_ + lane] = a1;
    sj_out[(long)row * HID_ + lane] = a2;
  }
}

// ---------------------------------------------------------------------------
// Kernel 2: pairwise delta (symmetrized), staged into d_out[0 .. B*N*N)
// One block = 16x16 tile-pair (tI <= tJ); each thread computes BOTH (i,j)
// and (j,i) orientations sharing the expensive diff@w_d.
// ---------------------------------------------------------------------------
__global__ __launch_bounds__(256) void pair_kernel(
    const float* __restrict__ h, const float* __restrict__ si, const float* __restrict__ sj,
    const float* __restrict__ ps_w1, const float* __restrict__ ps_b1,
    const float* __restrict__ ps_w2, const float* __restrict__ ps_b2,
    float* __restrict__ delta)
{
  int bidx = blockIdx.x;
  int b  = bidx / NTP;
  int tp = bidx % NTP;
  int tI = 0;
  while (tp >= NTILES - tI) { tp -= NTILES - tI; ++tI; }
  int tJ = tI + tp;
  const int i0 = tI * TILE, j0 = tJ * TILE;

  __shared__ float hI [TILE][HID_ + 1];
  __shared__ float hJ [TILE][HID_ + 1];
  __shared__ float SII[TILE][HID_ + 1];   // s_i rows of tile I
  __shared__ float SJI[TILE][HID_ + 1];   // s_j rows of tile I
  __shared__ float SIJ[TILE][HID_ + 1];   // s_i rows of tile J
  __shared__ float SJJ[TILE][HID_ + 1];   // s_j rows of tile J

  const int tid = threadIdx.x;
  #pragma unroll
  for (int rep = 0; rep < 4; ++rep) {
    int e = rep * 256 + tid;
    int r = e >> 6, c = e & 63;
    long gi = ((long)b * N_ + i0 + r) * HID_ + c;
    long gj = ((long)b * N_ + j0 + r) * HID_ + c;
    hI [r][c] = h [gi];  hJ [r][c] = h [gj];
    SII[r][c] = si[gi];  SJI[r][c] = sj[gi];
    SIJ[r][c] = si[gj];  SJJ[r][c] = sj[gj];
  }
  __syncthreads();

  const int ti = tid & (TILE - 1);
  const int tj = tid >> 4;
  const float* __restrict__ wd = ps_w1 + 2 * HID_ * HID_;   // rows [128,192)

  float acc[HID_];
  #pragma unroll
  for (int c = 0; c < HID_; ++c) acc[c] = 0.f;

  for (int k = 0; k < HID_; ++k) {
    float d = fabsf(hI[ti][k] - hJ[tj][k]);
    #pragma unroll
    for (int c = 0; c < HID_; ++c) acc[c] += d * wd[k * HID_ + c];   // uniform -> s_load
  }

  float a1 = ps_b2[0], a2 = a1;
  #pragma unroll
  for (int c = 0; c < HID_; ++c) {
    float base = acc[c] + ps_b1[c];
    float w2   = ps_w2[c];
    float p1 = base + SII[ti][c] + SJJ[tj][c];   // pre(i,j)
    float p2 = base + SIJ[tj][c] + SJI[ti][c];   // pre(j,i)
    a1 += fmaxf(p1, 0.f) * w2;
    a2 += fmaxf(p2, 0.f) * w2;
  }
  float sym = 0.5f * (tanhf(a1) + tanhf(a2));

  const int i = i0 + ti, j = j0 + tj;
  float* drow = delta + (long)b * N_ * N_;
  if (tI == tJ) {
    if (ti == tj) {
      drow[(long)i * N_ + i] = 0.f;
    } else if (ti < tj) {
      drow[(long)i * N_ + j] = sym;
      drow[(long)j * N_ + i] = sym;
    }
  } else {
    drow[(long)i * N_ + j] = sym;
    drow[(long)j * N_ + i] = sym;
  }
}

// ---------------------------------------------------------------------------
// Kernel 3: a_hybrid = relu(a_static + lam*delta) row-normalized, in place on
// d_out; also writes lam at d_out[B*N*N].
// ---------------------------------------------------------------------------
__global__ __launch_bounds__(256) void norm_kernel(
    const float* __restrict__ a_static, const float* __restrict__ raw_lambda,
    float* __restrict__ out)
{
  const int row = blockIdx.x;           // b*N + i
  const int i   = row % N_;
  const int tid = threadIdx.x;
  const float lam = 1.f / (1.f + expf(-raw_lambda[0]));

  const float* arow = a_static + (long)i * N_;
  float* drow = out + (long)row * N_;

  float vals[3];
  float s = 0.f;
  #pragma unroll
  for (int r = 0; r < 3; ++r) {
    int j = r * 256 + tid;
    float v = arow[j] + lam * drow[j];
    v = fmaxf(v, 0.f);
    vals[r] = v;
    s += v;
  }
  s = wave_sum64(s);
  __shared__ float ps[4];
  if ((tid & 63) == 0) ps[tid >> 6] = s;
  __syncthreads();
  float tot = ps[0] + ps[1] + ps[2] + ps[3];
  float inv = 1.f / fmaxf(tot, 1e-6f);
  #pragma unroll
  for (int r = 0; r < 3; ++r) {
    int j = r * 256 + tid;
    drow[j] = vals[r] * inv;
  }
  if (row == 0 && tid == 0) out[(long)B_ * N_ * N_] = lam;
}

// ---------------------------------------------------------------------------
extern "C" void kernel_launch(void* const* d_in, const int* in_sizes, int n_in,
                              void* d_out, int out_size, void* d_ws, size_t ws_size,
                              hipStream_t stream) {
  const float* x_hist     = (const float*)d_in[0];
  const float* x_mark     = (const float*)d_in[1];
  const float* a_static   = (const float*)d_in[2];
  const float* te_w1      = (const float*)d_in[3];
  const float* te_b1      = (const float*)d_in[4];
  const float* te_w2      = (const float*)d_in[5];
  const float* te_b2      = (const float*)d_in[6];
  const float* me_w1      = (const float*)d_in[7];
  const float* me_b1      = (const float*)d_in[8];
  const float* me_w2      = (const float*)d_in[9];
  const float* me_b2      = (const float*)d_in[10];
  const float* nf_w       = (const float*)d_in[11];
  const float* nf_b       = (const float*)d_in[12];
  const float* ps_w1      = (const float*)d_in[13];
  const float* ps_b1      = (const float*)d_in[14];
  const float* ps_w2      = (const float*)d_in[15];
  const float* ps_b2      = (const float*)d_in[16];
  const float* raw_lambda = (const float*)d_in[17];

  float* out = (float*)d_out;
  float* h   = (float*)d_ws;                 // B*N*64
  float* si  = h  + (long)B_ * N_ * HID_;    // B*N*64
  float* sj  = si + (long)B_ * N_ * HID_;    // B*N*64

  feat_kernel<<<B_ * N_, 64, 0, stream>>>(
      x_hist, x_mark, te_w1, te_b1, te_w2, te_b2,
      me_w1, me_b1, me_w2, me_b2, nf_w, nf_b, ps_w1, h, si, sj);

  pair_kernel<<<B_ * NTP, 256, 0, stream>>>(
      h, si, sj, ps_w1, ps_b1, ps_w2, ps_b2, out);

  norm_kernel<<<B_ * N_, 256, 0, stream>>>(a_static, raw_lambda, out);
}

// Round 2
// 50.894 us; speedup vs baseline: 1.9214x; 1.9214x over previous
//
#include <hip/hip_runtime.h>
#include <math.h>

#define B_ 2
#define N_ 768
#define T_ 96
#define FM_ 8
#define HID_ 64
#define TD_ 32
#define MD_ 32
#define TILE 16
#define NTILES (N_/TILE)            // 48
#define NTP (NTILES*(NTILES+1)/2)   // 1176
#define SSTR 66

typedef __attribute__((ext_vector_type(8))) short short8v;
typedef __attribute__((ext_vector_type(4))) float f32x4;

__device__ __forceinline__ unsigned short f2bf(float f){
  unsigned u = __builtin_bit_cast(unsigned, f);
  u += 0x7FFFu + ((u >> 16) & 1u);
  return (unsigned short)(u >> 16);
}

__device__ __forceinline__ float wave_sum64(float v){
  #pragma unroll
  for (int m = 32; m; m >>= 1) v += __shfl_xor(v, m);
  return v;
}
__device__ __forceinline__ float wave_max64(float v){
  #pragma unroll
  for (int m = 32; m; m >>= 1) v = fmaxf(v, __shfl_xor(v, m));
  return v;
}

// ---------------------------------------------------------------------------
// Kernel 0: pack W_d (ps_w1 rows [128,192)) into bf16 B-fragment order.
// Fragment q = nt*2+s, lane l, elem jj  ->  B[k = s*32+(l>>4)*8+jj][c = (l&15)+16nt]
// ---------------------------------------------------------------------------
__global__ __launch_bounds__(512) void prep_wd(const float* __restrict__ ps_w1,
                                               unsigned short* __restrict__ wdf){
  const int tid  = threadIdx.x;          // 0..511
  const int lane = tid & 63;
  const int q    = tid >> 6;             // nt*2+s
  const int nt   = q >> 1, s = q & 1;
  const int col  = (lane & 15) + 16*nt;
  const int k0   = s*32 + ((lane >> 4) << 3);
  #pragma unroll
  for (int jj = 0; jj < 8; ++jj){
    float v = ps_w1[(2*HID_ + k0 + jj)*HID_ + col];
    wdf[(q*64 + lane)*8 + jj] = f2bf(v);
  }
}

// ---------------------------------------------------------------------------
// Kernel 1: per-(b,n) features -> h, s_i, s_j   (1536 blocks x 64 threads)
// ---------------------------------------------------------------------------
__global__ __launch_bounds__(64) void feat_kernel(
    const float* __restrict__ x_hist, const float* __restrict__ x_mark,
    const float* __restrict__ te_w1, const float* __restrict__ te_b1,
    const float* __restrict__ te_w2, const float* __restrict__ te_b2,
    const float* __restrict__ me_w1, const float* __restrict__ me_b1,
    const float* __restrict__ me_w2, const float* __restrict__ me_b2,
    const float* __restrict__ nf_w,  const float* __restrict__ nf_b,
    const float* __restrict__ ps_w1,
    float* __restrict__ h_out, float* __restrict__ si_out, float* __restrict__ sj_out)
{
  const int row  = blockIdx.x;          // b*N + n
  const int lane = threadIdx.x;         // 0..63

  __shared__ float st[3];
  __shared__ float ms[FM_];
  __shared__ float t1s[TD_];
  __shared__ float m1s[MD_];
  __shared__ float hc[HID_];
  __shared__ float hs[HID_];

  const float* xh = x_hist + (long)row * T_;
  float s  = xh[lane];
  float mx = s;
  if (lane < T_ - 64) { float v = xh[lane + 64]; s += v; mx = fmaxf(mx, v); }
  s  = wave_sum64(s);
  mx = wave_max64(mx);
  if (lane == 0) { st[0] = xh[T_ - 1]; st[1] = s * (1.0f / T_); st[2] = mx; }

  const float* xm = x_mark + (long)row * T_ * FM_;
  float msv = 0.f;
  #pragma unroll
  for (int k = 0; k < 12; ++k) msv += xm[lane + 64 * k];
  msv += __shfl_xor(msv, 8);
  msv += __shfl_xor(msv, 16);
  msv += __shfl_xor(msv, 32);
  if (lane < FM_) ms[lane] = msv * (1.0f / T_);
  __syncthreads();

  if (lane < TD_) {
    float a = te_b1[lane];
    #pragma unroll
    for (int k = 0; k < 3; ++k) a += st[k] * te_w1[k * TD_ + lane];
    t1s[lane] = fmaxf(a, 0.f);
    float am = me_b1[lane];
    #pragma unroll
    for (int k = 0; k < FM_; ++k) am += ms[k] * me_w1[k * MD_ + lane];
    m1s[lane] = fmaxf(am, 0.f);
  }
  __syncthreads();
  if (lane < TD_) {
    float a = te_b2[lane];
    #pragma unroll
    for (int k = 0; k < TD_; ++k) a += t1s[k] * te_w2[k * TD_ + lane];
    hc[lane] = a;
    float am = me_b2[lane];
    #pragma unroll
    for (int k = 0; k < MD_; ++k) am += m1s[k] * me_w2[k * MD_ + lane];
    hc[TD_ + lane] = am;
  }
  __syncthreads();
  {
    float a = nf_b[lane];
    #pragma unroll
    for (int k = 0; k < HID_; ++k) a += hc[k] * nf_w[k * HID_ + lane];
    float hv = fmaxf(a, 0.f);
    hs[lane] = hv;
    h_out[(long)row * HID_ + lane] = hv;
  }
  __syncthreads();
  {
    float a1 = 0.f, a2 = 0.f;
    #pragma unroll
    for (int k = 0; k < HID_; ++k) {
      float hv = hs[k];
      a1 += hv * ps_w1[k * HID_ + lane];
      a2 += hv * ps_w1[(HID_ + k) * HID_ + lane];
    }
    si_out[(long)row * HID_ + lane] = a1;
    sj_out[(long)row * HID_ + lane] = a2;
  }
}

// ---------------------------------------------------------------------------
// Kernel 2: pairwise delta via MFMA, staged into d_out[0 .. B*N*N)
// Block = 16x16 tile-pair (tI<=tJ), 4 waves; wave w owns i-rows 4w..4w+3.
// Per m (one i): A = |h_i - h_J| (16 j-rows x 64 k) in fragment regs,
// C = A @ W_d via 8 mfma_16x16x32_bf16; epilogue does BOTH orientations.
// ---------------------------------------------------------------------------
__global__ __launch_bounds__(256) void pair_kernel(
    const float* __restrict__ h, const float* __restrict__ si, const float* __restrict__ sj,
    const float* __restrict__ ps_b1, const float* __restrict__ ps_w2,
    const float* __restrict__ ps_b2, const unsigned short* __restrict__ wdf,
    float* __restrict__ delta)
{
  int bidx = blockIdx.x;
  int b  = bidx / NTP;
  int tp = bidx % NTP;
  int tI = 0;
  while (tp >= NTILES - tI) { tp -= NTILES - tI; ++tI; }
  int tJ = tI + tp;
  const int i0 = tI * TILE, j0 = tJ * TILE;

  __shared__ float hI  [TILE][HID_];       // broadcast reads
  __shared__ float hJT [HID_][TILE + 1];   // transposed, 2-way max
  __shared__ float SIIb[TILE][SSTR];       // s_i[I] + b1
  __shared__ float SJI_[TILE][SSTR];       // s_j[I]
  __shared__ float SIJb[TILE][SSTR];       // s_i[J] + b1
  __shared__ float SJJ_[TILE][SSTR];       // s_j[J]

  const int tid  = threadIdx.x;
  const int lane = tid & 63;
  const int w    = tid >> 6;

  #pragma unroll
  for (int rep = 0; rep < 4; ++rep) {
    int e = rep * 256 + tid;
    int r = e >> 6, c = e & 63;
    long gi = ((long)b * N_ + i0 + r) * HID_ + c;
    long gj = ((long)b * N_ + j0 + r) * HID_ + c;
    float b1c = ps_b1[c];
    hI [r][c]  = h[gi];
    hJT[c][r]  = h[gj];
    SIIb[r][c] = si[gi] + b1c;
    SJI_[r][c] = sj[gi];
    SIJb[r][c] = si[gj] + b1c;
    SJJ_[r][c] = sj[gj];
  }
  __syncthreads();

  const int g   = lane >> 4;     // 0..3 (k-group / j-row group)
  const int c16 = lane & 15;

  // B fragments (bf16 W_d, prepacked)
  short8v bfrag[8];
  const short8v* wdp = (const short8v*)wdf;
  #pragma unroll
  for (int q = 0; q < 8; ++q) bfrag[q] = wdp[q*64 + lane];

  // j-side hoists (m-independent)
  float hJv[2][8];
  #pragma unroll
  for (int s = 0; s < 2; ++s)
    #pragma unroll
    for (int jj = 0; jj < 8; ++jj)
      hJv[s][jj] = hJT[s*32 + g*8 + jj][c16];

  float sJJv[4][4], sIJv[4][4];
  #pragma unroll
  for (int r = 0; r < 4; ++r)
    #pragma unroll
    for (int nt = 0; nt < 4; ++nt){
      sJJv[r][nt] = SJJ_[g*4 + r][c16 + 16*nt];
      sIJv[r][nt] = SIJb[g*4 + r][c16 + 16*nt];
    }

  float w2v[4];
  #pragma unroll
  for (int nt = 0; nt < 4; ++nt) w2v[nt] = ps_w2[c16 + 16*nt];
  const float b2 = ps_b2[0];

  float* drow = delta + (long)b * N_ * N_;

  #pragma unroll
  for (int m = 0; m < 4; ++m) {
    const int iloc = w*4 + m;
    const int i = i0 + iloc;

    // A fragments: row (=j) = c16, k = g*8+jj+32s
    short8v afr[2];
    #pragma unroll
    for (int s = 0; s < 2; ++s)
      #pragma unroll
      for (int jj = 0; jj < 8; ++jj){
        float hv = hI[iloc][s*32 + g*8 + jj];       // group-uniform broadcast
        afr[s][jj] = (short)f2bf(fabsf(hv - hJv[s][jj]));
      }

    f32x4 acc[4];
    #pragma unroll
    for (int nt = 0; nt < 4; ++nt) acc[nt] = (f32x4){0.f,0.f,0.f,0.f};
    #pragma unroll
    for (int s = 0; s < 2; ++s)
      #pragma unroll
      for (int nt = 0; nt < 4; ++nt)
        acc[nt] = __builtin_amdgcn_mfma_f32_16x16x32_bf16(afr[s], bfrag[nt*2+s], acc[nt], 0, 0, 0);

    // epilogue: C row = j = g*4+r, col c = c16+16nt
    float a1p[4] = {0.f,0.f,0.f,0.f}, a2p[4] = {0.f,0.f,0.f,0.f};
    #pragma unroll
    for (int nt = 0; nt < 4; ++nt){
      float sIIc = SIIb[iloc][c16 + 16*nt];   // broadcast
      float sJIc = SJI_[iloc][c16 + 16*nt];   // broadcast
      float w2c  = w2v[nt];
      #pragma unroll
      for (int r = 0; r < 4; ++r){
        float av = acc[nt][r];
        float p1 = av + sIIc + sJJv[r][nt];   // pre(i,j)
        float p2 = av + sIJv[r][nt] + sJIc;   // pre(j,i)
        a1p[r] += fmaxf(p1, 0.f) * w2c;
        a2p[r] += fmaxf(p2, 0.f) * w2c;
      }
    }
    #pragma unroll
    for (int r = 0; r < 4; ++r){
      #pragma unroll
      for (int mask = 1; mask < 16; mask <<= 1){
        a1p[r] += __shfl_xor(a1p[r], mask);
        a2p[r] += __shfl_xor(a2p[r], mask);
      }
    }
    if (c16 < 4) {
      int r = c16;
      int j = j0 + g*4 + r;
      float t1 = tanhf(a1p[r] + b2);
      float t2 = tanhf(a2p[r] + b2);
      float sym = 0.5f*(t1 + t2);
      if (i == j) {
        drow[(long)i * N_ + i] = 0.f;
      } else if (tI < tJ || i < j) {
        drow[(long)i * N_ + j] = sym;
        drow[(long)j * N_ + i] = sym;
      }
    }
  }
}

// ---------------------------------------------------------------------------
// Kernel 3: a_hybrid = relu(a_static + lam*delta) row-normalized, in place.
// ---------------------------------------------------------------------------
__global__ __launch_bounds__(256) void norm_kernel(
    const float* __restrict__ a_static, const float* __restrict__ raw_lambda,
    float* __restrict__ out)
{
  const int row = blockIdx.x;           // b*N + i
  const int i   = row % N_;
  const int tid = threadIdx.x;
  const float lam = 1.f / (1.f + expf(-raw_lambda[0]));

  const float* arow = a_static + (long)i * N_;
  float* drow = out + (long)row * N_;

  float vals[3];
  float s = 0.f;
  #pragma unroll
  for (int r = 0; r < 3; ++r) {
    int j = r * 256 + tid;
    float v = arow[j] + lam * drow[j];
    v = fmaxf(v, 0.f);
    vals[r] = v;
    s += v;
  }
  s = wave_sum64(s);
  __shared__ float ps[4];
  if ((tid & 63) == 0) ps[tid >> 6] = s;
  __syncthreads();
  float tot = ps[0] + ps[1] + ps[2] + ps[3];
  float inv = 1.f / fmaxf(tot, 1e-6f);
  #pragma unroll
  for (int r = 0; r < 3; ++r) {
    int j = r * 256 + tid;
    drow[j] = vals[r] * inv;
  }
  if (row == 0 && tid == 0) out[(long)B_ * N_ * N_] = lam;
}

// ---------------------------------------------------------------------------
extern "C" void kernel_launch(void* const* d_in, const int* in_sizes, int n_in,
                              void* d_out, int out_size, void* d_ws, size_t ws_size,
                              hipStream_t stream) {
  const float* x_hist     = (const float*)d_in[0];
  const float* x_mark     = (const float*)d_in[1];
  const float* a_static   = (const float*)d_in[2];
  const float* te_w1      = (const float*)d_in[3];
  const float* te_b1      = (const float*)d_in[4];
  const float* te_w2      = (const float*)d_in[5];
  const float* te_b2      = (const float*)d_in[6];
  const float* me_w1      = (const float*)d_in[7];
  const float* me_b1      = (const float*)d_in[8];
  const float* me_w2      = (const float*)d_in[9];
  const float* me_b2      = (const float*)d_in[10];
  const float* nf_w       = (const float*)d_in[11];
  const float* nf_b       = (const float*)d_in[12];
  const float* ps_w1      = (const float*)d_in[13];
  const float* ps_b1      = (const float*)d_in[14];
  const float* ps_w2      = (const float*)d_in[15];
  const float* ps_b2      = (const float*)d_in[16];
  const float* raw_lambda = (const float*)d_in[17];

  float* out = (float*)d_out;
  float* h   = (float*)d_ws;                 // B*N*64 f32
  float* si  = h  + (long)B_ * N_ * HID_;
  float* sj  = si + (long)B_ * N_ * HID_;
  unsigned short* wdf = (unsigned short*)(sj + (long)B_ * N_ * HID_);  // 4096 bf16

  prep_wd<<<1, 512, 0, stream>>>(ps_w1, wdf);

  feat_kernel<<<B_ * N_, 64, 0, stream>>>(
      x_hist, x_mark, te_w1, te_b1, te_w2, te_b2,
      me_w1, me_b1, me_w2, me_b2, nf_w, nf_b, ps_w1, h, si, sj);

  pair_kernel<<<B_ * NTP, 256, 0, stream>>>(
      h, si, sj, ps_b1, ps_w2, ps_b2, wdf, out);

  norm_kernel<<<B_ * N_, 256, 0, stream>>>(a_static, raw_lambda, out);
}

// Round 4
// 35.971 us; speedup vs baseline: 2.7185x; 1.4149x over previous
//
#include <hip/hip_runtime.h>
#include <hip/hip_bf16.h>
#include <math.h>

#define B_ 2
#define N_ 768
#define T_ 96
#define FM_ 8
#define HID_ 64
#define TD_ 32
#define MD_ 32
#define TILE 16
#define NTILES (N_/TILE)            // 48
#define NTP (NTILES*(NTILES+1)/2)   // 1176
#define SSTR 68

typedef __attribute__((ext_vector_type(8))) short short8v;
typedef __attribute__((ext_vector_type(4))) float f32x4;
typedef __attribute__((ext_vector_type(4))) unsigned int uint4v;

__device__ __forceinline__ unsigned int pack_bf2(float d0, float d1){
  __hip_bfloat162 t = __float22bfloat162_rn(make_float2(d0, d1));
  unsigned int u;
  __builtin_memcpy(&u, &t, 4);
  return u;
}

__device__ __forceinline__ float ftanh(float x){
  float e = __expf(2.f * x);
  return 1.f - 2.f * __builtin_amdgcn_rcpf(e + 1.f);
}

__device__ __forceinline__ float wave_sum64(float v){
  #pragma unroll
  for (int m = 32; m; m >>= 1) v += __shfl_xor(v, m);
  return v;
}
__device__ __forceinline__ float wave_max64(float v){
  #pragma unroll
  for (int m = 32; m; m >>= 1) v = fmaxf(v, __shfl_xor(v, m));
  return v;
}

// ---------------------------------------------------------------------------
// Kernel 1: per-(b,n) features -> h, s_i, s_j  (1536 blocks x 64 threads)
// Blocks [B*N, B*N+8): pack W_d (ps_w1 rows [128,192)) into bf16 fragments.
// Fragment q = nt*2+s, lane l, elem jj -> Wd[k=s*32+(l>>4)*8+jj][c=(l&15)+16nt]
// ---------------------------------------------------------------------------
__global__ __launch_bounds__(64) void feat_kernel(
    const float* __restrict__ x_hist, const float* __restrict__ x_mark,
    const float* __restrict__ te_w1, const float* __restrict__ te_b1,
    const float* __restrict__ te_w2, const float* __restrict__ te_b2,
    const float* __restrict__ me_w1, const float* __restrict__ me_b1,
    const float* __restrict__ me_w2, const float* __restrict__ me_b2,
    const float* __restrict__ nf_w,  const float* __restrict__ nf_b,
    const float* __restrict__ ps_w1,
    float* __restrict__ h_out, float* __restrict__ si_out, float* __restrict__ sj_out,
    unsigned short* __restrict__ wdf)
{
  const int lane = threadIdx.x;         // 0..63

  if (blockIdx.x >= B_ * N_) {          // W_d packing blocks
    const int q  = blockIdx.x - B_ * N_;   // 0..7 = nt*2+s
    const int nt = q >> 1, s = q & 1;
    const int col = (lane & 15) + 16 * nt;
    const int k0  = s * 32 + ((lane >> 4) << 3);
    #pragma unroll
    for (int jj = 0; jj < 8; ++jj) {
      float v = ps_w1[(2 * HID_ + k0 + jj) * HID_ + col];
      __hip_bfloat16 bv = __float2bfloat16(v);
      unsigned short us;
      __builtin_memcpy(&us, &bv, 2);
      wdf[(q * 64 + lane) * 8 + jj] = us;
    }
    return;
  }

  const int row = blockIdx.x;           // b*N + n

  __shared__ float st[3];
  __shared__ float ms[FM_];
  __shared__ float t1s[TD_];
  __shared__ float m1s[MD_];
  __shared__ float hc[HID_];
  __shared__ float hs[HID_];

  const float* xh = x_hist + (long)row * T_;
  float s  = xh[lane];
  float mx = s;
  if (lane < T_ - 64) { float v = xh[lane + 64]; s += v; mx = fmaxf(mx, v); }
  s  = wave_sum64(s);
  mx = wave_max64(mx);
  if (lane == 0) { st[0] = xh[T_ - 1]; st[1] = s * (1.0f / T_); st[2] = mx; }

  const float* xm = x_mark + (long)row * T_ * FM_;
  float msv = 0.f;
  #pragma unroll
  for (int k = 0; k < 12; ++k) msv += xm[lane + 64 * k];
  msv += __shfl_xor(msv, 8);
  msv += __shfl_xor(msv, 16);
  msv += __shfl_xor(msv, 32);
  if (lane < FM_) ms[lane] = msv * (1.0f / T_);
  __syncthreads();

  if (lane < TD_) {
    float a = te_b1[lane];
    #pragma unroll
    for (int k = 0; k < 3; ++k) a += st[k] * te_w1[k * TD_ + lane];
    t1s[lane] = fmaxf(a, 0.f);
    float am = me_b1[lane];
    #pragma unroll
    for (int k = 0; k < FM_; ++k) am += ms[k] * me_w1[k * MD_ + lane];
    m1s[lane] = fmaxf(am, 0.f);
  }
  __syncthreads();
  if (lane < TD_) {
    float a = te_b2[lane];
    #pragma unroll
    for (int k = 0; k < TD_; ++k) a += t1s[k] * te_w2[k * TD_ + lane];
    hc[lane] = a;
    float am = me_b2[lane];
    #pragma unroll
    for (int k = 0; k < MD_; ++k) am += m1s[k] * me_w2[k * MD_ + lane];
    hc[TD_ + lane] = am;
  }
  __syncthreads();
  {
    float a = nf_b[lane];
    #pragma unroll
    for (int k = 0; k < HID_; ++k) a += hc[k] * nf_w[k * HID_ + lane];
    float hv = fmaxf(a, 0.f);
    hs[lane] = hv;
    h_out[(long)row * HID_ + lane] = hv;
  }
  __syncthreads();
  {
    float a1 = 0.f, a2 = 0.f;
    #pragma unroll
    for (int k = 0; k < HID_; ++k) {
      float hv = hs[k];
      a1 += hv * ps_w1[k * HID_ + lane];
      a2 += hv * ps_w1[(HID_ + k) * HID_ + lane];
    }
    si_out[(long)row * HID_ + lane] = a1;
    sj_out[(long)row * HID_ + lane] = a2;
  }
}

// ---------------------------------------------------------------------------
// Kernel 2: pairwise delta via transposed MFMA (E = Wd^T @ diff^T).
// Block = 16x16 tile-pair (tI<=tJ), 4 waves; wave w owns i-rows 4w..4w+3.
// Output fragment: lane holds j = lane&15, c = 16*mt + 4*(lane>>4) + reg ->
// c-dot reduces in-lane + 2 shfls; tanh vectorizes over 16 j's.
// ---------------------------------------------------------------------------
__global__ __launch_bounds__(256) void pair_kernel(
    const float* __restrict__ h, const float* __restrict__ si, const float* __restrict__ sj,
    const float* __restrict__ ps_b1, const float* __restrict__ ps_w2,
    const float* __restrict__ ps_b2, const unsigned short* __restrict__ wdf,
    float* __restrict__ delta)
{
  int bidx = blockIdx.x;
  int b  = bidx / NTP;
  int tp = bidx % NTP;
  int tI = 0;
  while (tp >= NTILES - tI) { tp -= NTILES - tI; ++tI; }
  int tJ = tI + tp;
  const int i0 = tI * TILE, j0 = tJ * TILE;

  __shared__ float hI  [TILE][HID_];       // group-broadcast reads
  __shared__ float hJT [HID_][TILE + 1];   // transposed h_J
  __shared__ float SIIb[TILE][SSTR];       // s_i[I] + b1
  __shared__ float SJI_[TILE][SSTR];       // s_j[I]
  __shared__ float SIJb[TILE][SSTR];       // s_i[J] + b1
  __shared__ float SJJ_[TILE][SSTR];       // s_j[J]
  __shared__ float w2s [HID_];

  const int tid  = threadIdx.x;
  const int lane = tid & 63;
  const int w    = tid >> 6;

  {
    const int r  = tid >> 4;
    const int c4 = (tid & 15) * 4;
    const f32x4 b14 = *(const f32x4*)(ps_b1 + c4);
    const long gi = ((long)b * N_ + i0 + r) * HID_ + c4;
    const long gj = ((long)b * N_ + j0 + r) * HID_ + c4;
    f32x4 vhi = *(const f32x4*)(h  + gi);
    f32x4 vhj = *(const f32x4*)(h  + gj);
    f32x4 vii = *(const f32x4*)(si + gi);
    f32x4 vji = *(const f32x4*)(sj + gi);
    f32x4 vij = *(const f32x4*)(si + gj);
    f32x4 vjj = *(const f32x4*)(sj + gj);
    *(f32x4*)&hI  [r][c4] = vhi;
    #pragma unroll
    for (int q = 0; q < 4; ++q) hJT[c4 + q][r] = vhj[q];
    *(f32x4*)&SIIb[r][c4] = vii + b14;
    *(f32x4*)&SJI_[r][c4] = vji;
    *(f32x4*)&SIJb[r][c4] = vij + b14;
    *(f32x4*)&SJJ_[r][c4] = vjj;
    if (tid < 16) *(f32x4*)&w2s[tid * 4] = *(const f32x4*)(ps_w2 + tid * 4);
  }
  const float b2 = ps_b2[0];
  __syncthreads();

  const int g   = lane >> 4;     // 0..3
  const int c16 = lane & 15;     // = j within tile

  // Wd fragments (A operand), prepacked
  short8v wfr[8];
  const short8v* wdp = (const short8v*)wdf;
  #pragma unroll
  for (int q = 0; q < 8; ++q) wfr[q] = wdp[q * 64 + lane];

  // h_J values this lane needs for B-fragment build (j = c16, k = 32s+8g+jj)
  float hJv[2][8];
  #pragma unroll
  for (int s = 0; s < 2; ++s)
    #pragma unroll
    for (int jj = 0; jj < 8; ++jj)
      hJv[s][jj] = hJT[32 * s + 8 * g + jj][c16];

  float* drow = delta + (long)b * N_ * N_;

  #pragma unroll
  for (int m = 0; m < 4; ++m) {
    const int iloc = w * 4 + m;
    const int i = i0 + iloc;

    // B-fragments: |h_i - h_j|, col=j=c16, k=32s+8g+jj  (v_cvt_pk_bf16_f32)
    short8v afr[2];
    #pragma unroll
    for (int s = 0; s < 2; ++s) {
      f32x4 ha = *(const f32x4*)&hI[iloc][32 * s + 8 * g];
      f32x4 hb = *(const f32x4*)&hI[iloc][32 * s + 8 * g + 4];
      uint4v uv;
      #pragma unroll
      for (int p = 0; p < 2; ++p) {
        float d0 = fabsf(ha[2*p]   - hJv[s][2*p]);
        float d1 = fabsf(ha[2*p+1] - hJv[s][2*p+1]);
        uv[p] = pack_bf2(d0, d1);
      }
      #pragma unroll
      for (int p = 0; p < 2; ++p) {
        float d0 = fabsf(hb[2*p]   - hJv[s][4 + 2*p]);
        float d1 = fabsf(hb[2*p+1] - hJv[s][4 + 2*p+1]);
        uv[2 + p] = pack_bf2(d0, d1);
      }
      afr[s] = __builtin_bit_cast(short8v, uv);
    }

    f32x4 acc[4];
    #pragma unroll
    for (int mt = 0; mt < 4; ++mt) acc[mt] = (f32x4){0.f, 0.f, 0.f, 0.f};
    #pragma unroll
    for (int s = 0; s < 2; ++s)
      #pragma unroll
      for (int mt = 0; mt < 4; ++mt)
        acc[mt] = __builtin_amdgcn_mfma_f32_16x16x32_bf16(wfr[2 * mt + s], afr[s], acc[mt], 0, 0, 0);

    // epilogue: lane holds j=c16, c = 16mt + 4g + r
    float a1 = 0.f, a2 = 0.f;
    #pragma unroll
    for (int mt = 0; mt < 4; ++mt) {
      const int cb = 16 * mt + 4 * g;
      f32x4 sII4 = *(const f32x4*)&SIIb[iloc][cb];   // broadcast per group
      f32x4 sJI4 = *(const f32x4*)&SJI_[iloc][cb];
      f32x4 sJJ4 = *(const f32x4*)&SJJ_[c16][cb];    // per-lane gather
      f32x4 sIJ4 = *(const f32x4*)&SIJb[c16][cb];
      f32x4 w24  = *(const f32x4*)&w2s[cb];
      #pragma unroll
      for (int r = 0; r < 4; ++r) {
        float av = acc[mt][r];
        a1 += fmaxf(av + sII4[r] + sJJ4[r], 0.f) * w24[r];   // pre(i,j)
        a2 += fmaxf(av + sJI4[r] + sIJ4[r], 0.f) * w24[r];   // pre(j,i)
      }
    }
    a1 += __shfl_xor(a1, 16);  a1 += __shfl_xor(a1, 32);
    a2 += __shfl_xor(a2, 16);  a2 += __shfl_xor(a2, 32);

    if (g == 0) {
      const int j = j0 + c16;
      float sym = 0.5f * (ftanh(a1 + b2) + ftanh(a2 + b2));
      float val = (i == j) ? 0.f : sym;
      drow[(long)i * N_ + j] = val;
      drow[(long)j * N_ + i] = val;
    }
  }
}

// ---------------------------------------------------------------------------
// Kernel 3: a_hybrid = relu(a_static + lam*delta) row-normalized, in place.
// ---------------------------------------------------------------------------
__global__ __launch_bounds__(256) void norm_kernel(
    const float* __restrict__ a_static, const float* __restrict__ raw_lambda,
    float* __restrict__ out)
{
  const int row = blockIdx.x;           // b*N + i
  const int i   = row % N_;
  const int tid = threadIdx.x;
  const float lam = 1.f / (1.f + expf(-raw_lambda[0]));

  const float* arow = a_static + (long)i * N_;
  float* drow = out + (long)row * N_;

  float vals[3];
  float s = 0.f;
  #pragma unroll
  for (int r = 0; r < 3; ++r) {
    int j = r * 256 + tid;
    float v = arow[j] + lam * drow[j];
    v = fmaxf(v, 0.f);
    vals[r] = v;
    s += v;
  }
  s = wave_sum64(s);
  __shared__ float ps[4];
  if ((tid & 63) == 0) ps[tid >> 6] = s;
  __syncthreads();
  float tot = ps[0] + ps[1] + ps[2] + ps[3];
  float inv = 1.f / fmaxf(tot, 1e-6f);
  #pragma unroll
  for (int r = 0; r < 3; ++r) {
    int j = r * 256 + tid;
    drow[j] = vals[r] * inv;
  }
  if (row == 0 && tid == 0) out[(long)B_ * N_ * N_] = lam;
}

// ---------------------------------------------------------------------------
extern "C" void kernel_launch(void* const* d_in, const int* in_sizes, int n_in,
                              void* d_out, int out_size, void* d_ws, size_t ws_size,
                              hipStream_t stream) {
  const float* x_hist     = (const float*)d_in[0];
  const float* x_mark     = (const float*)d_in[1];
  const float* a_static   = (const float*)d_in[2];
  const float* te_w1      = (const float*)d_in[3];
  const float* te_b1      = (const float*)d_in[4];
  const float* te_w2      = (const float*)d_in[5];
  const float* te_b2      = (const float*)d_in[6];
  const float* me_w1      = (const float*)d_in[7];
  const float* me_b1      = (const float*)d_in[8];
  const float* me_w2      = (const float*)d_in[9];
  const float* me_b2      = (const float*)d_in[10];
  const float* nf_w       = (const float*)d_in[11];
  const float* nf_b       = (const float*)d_in[12];
  const float* ps_w1      = (const float*)d_in[13];
  const float* ps_b1      = (const float*)d_in[14];
  const float* ps_w2      = (const float*)d_in[15];
  const float* ps_b2      = (const float*)d_in[16];
  const float* raw_lambda = (const float*)d_in[17];

  float* out = (float*)d_out;
  float* h   = (float*)d_ws;                 // B*N*64 f32
  float* si  = h  + (long)B_ * N_ * HID_;
  float* sj  = si + (long)B_ * N_ * HID_;
  unsigned short* wdf = (unsigned short*)(sj + (long)B_ * N_ * HID_);  // 4096 bf16

  feat_kernel<<<B_ * N_ + 8, 64, 0, stream>>>(
      x_hist, x_mark, te_w1, te_b1, te_w2, te_b2,
      me_w1, me_b1, me_w2, me_b2, nf_w, nf_b, ps_w1, h, si, sj, wdf);

  pair_kernel<<<B_ * NTP, 256, 0, stream>>>(
      h, si, sj, ps_b1, ps_w2, ps_b2, wdf, out);

  norm_kernel<<<B_ * N_, 256, 0, stream>>>(a_static, raw_lambda, out);
}

// Round 5
// 35.599 us; speedup vs baseline: 2.7469x; 1.0104x over previous
//
#include <hip/hip_runtime.h>
#include <hip/hip_bf16.h>
#include <math.h>

#define B_ 2
#define N_ 768
#define T_ 96
#define FM_ 8
#define HID_ 64
#define TD_ 32
#define MD_ 32
#define TILE 16
#define TI32 32
#define NTILES (N_/TILE)            // 48
#define PERB 600                    // sum_{a=0}^{23} (48-2a)
#define SSTR 68

typedef __attribute__((ext_vector_type(8))) short short8v;
typedef __attribute__((ext_vector_type(4))) float f32x4;
typedef __attribute__((ext_vector_type(4))) unsigned int uint4v;

__device__ __forceinline__ unsigned int pack_bf2(float d0, float d1){
  __hip_bfloat162 t = __float22bfloat162_rn(make_float2(d0, d1));
  unsigned int u;
  __builtin_memcpy(&u, &t, 4);
  return u;
}

__device__ __forceinline__ float ftanh(float x){
  float e = __expf(2.f * x);
  return 1.f - 2.f * __builtin_amdgcn_rcpf(e + 1.f);
}

__device__ __forceinline__ float wave_sum64(float v){
  #pragma unroll
  for (int m = 32; m; m >>= 1) v += __shfl_xor(v, m);
  return v;
}
__device__ __forceinline__ float wave_max64(float v){
  #pragma unroll
  for (int m = 32; m; m >>= 1) v = fmaxf(v, __shfl_xor(v, m));
  return v;
}

// ---------------------------------------------------------------------------
// Kernel 1: per-(b,n) features -> h, s_i, s_j  (1536 blocks x 64 threads)
// Blocks [B*N, B*N+8): pack W_d (ps_w1 rows [128,192)) into bf16 fragments.
// Fragment q = nt*2+s, lane l, elem jj -> Wd[k=s*32+(l>>4)*8+jj][c=(l&15)+16nt]
// ---------------------------------------------------------------------------
__global__ __launch_bounds__(64) void feat_kernel(
    const float* __restrict__ x_hist, const float* __restrict__ x_mark,
    const float* __restrict__ te_w1, const float* __restrict__ te_b1,
    const float* __restrict__ te_w2, const float* __restrict__ te_b2,
    const float* __restrict__ me_w1, const float* __restrict__ me_b1,
    const float* __restrict__ me_w2, const float* __restrict__ me_b2,
    const float* __restrict__ nf_w,  const float* __restrict__ nf_b,
    const float* __restrict__ ps_w1,
    float* __restrict__ h_out, float* __restrict__ si_out, float* __restrict__ sj_out,
    unsigned short* __restrict__ wdf)
{
  const int lane = threadIdx.x;         // 0..63

  if (blockIdx.x >= B_ * N_) {          // W_d packing blocks
    const int q  = blockIdx.x - B_ * N_;   // 0..7 = nt*2+s
    const int nt = q >> 1, s = q & 1;
    const int col = (lane & 15) + 16 * nt;
    const int k0  = s * 32 + ((lane >> 4) << 3);
    #pragma unroll
    for (int jj = 0; jj < 8; ++jj) {
      float v = ps_w1[(2 * HID_ + k0 + jj) * HID_ + col];
      __hip_bfloat16 bv = __float2bfloat16(v);
      unsigned short us;
      __builtin_memcpy(&us, &bv, 2);
      wdf[(q * 64 + lane) * 8 + jj] = us;
    }
    return;
  }

  const int row = blockIdx.x;           // b*N + n

  __shared__ float st[3];
  __shared__ float ms[FM_];
  __shared__ float t1s[TD_];
  __shared__ float m1s[MD_];
  __shared__ float hc[HID_];
  __shared__ float hs[HID_];

  const float* xh = x_hist + (long)row * T_;
  float s  = xh[lane];
  float mx = s;
  if (lane < T_ - 64) { float v = xh[lane + 64]; s += v; mx = fmaxf(mx, v); }
  s  = wave_sum64(s);
  mx = wave_max64(mx);
  if (lane == 0) { st[0] = xh[T_ - 1]; st[1] = s * (1.0f / T_); st[2] = mx; }

  const float* xm = x_mark + (long)row * T_ * FM_;
  float msv = 0.f;
  #pragma unroll
  for (int k = 0; k < 12; ++k) msv += xm[lane + 64 * k];
  msv += __shfl_xor(msv, 8);
  msv += __shfl_xor(msv, 16);
  msv += __shfl_xor(msv, 32);
  if (lane < FM_) ms[lane] = msv * (1.0f / T_);
  __syncthreads();

  if (lane < TD_) {
    float a = te_b1[lane];
    #pragma unroll
    for (int k = 0; k < 3; ++k) a += st[k] * te_w1[k * TD_ + lane];
    t1s[lane] = fmaxf(a, 0.f);
    float am = me_b1[lane];
    #pragma unroll
    for (int k = 0; k < FM_; ++k) am += ms[k] * me_w1[k * MD_ + lane];
    m1s[lane] = fmaxf(am, 0.f);
  }
  __syncthreads();
  if (lane < TD_) {
    float a = te_b2[lane];
    #pragma unroll
    for (int k = 0; k < TD_; ++k) a += t1s[k] * te_w2[k * TD_ + lane];
    hc[lane] = a;
    float am = me_b2[lane];
    #pragma unroll
    for (int k = 0; k < MD_; ++k) am += m1s[k] * me_w2[k * MD_ + lane];
    hc[TD_ + lane] = am;
  }
  __syncthreads();
  {
    float a = nf_b[lane];
    #pragma unroll
    for (int k = 0; k < HID_; ++k) a += hc[k] * nf_w[k * HID_ + lane];
    float hv = fmaxf(a, 0.f);
    hs[lane] = hv;
    h_out[(long)row * HID_ + lane] = hv;
  }
  __syncthreads();
  {
    float a1 = 0.f, a2 = 0.f;
    #pragma unroll
    for (int k = 0; k < HID_; ++k) {
      float hv = hs[k];
      a1 += hv * ps_w1[k * HID_ + lane];
      a2 += hv * ps_w1[(HID_ + k) * HID_ + lane];
    }
    si_out[(long)row * HID_ + lane] = a1;
    sj_out[(long)row * HID_ + lane] = a2;
  }
}

// ---------------------------------------------------------------------------
// Kernel 2: pairwise delta via transposed MFMA (E = Wd^T @ diff^T).
// Block = 32 i-rows x 16 j-rows, 4 waves; wave w owns i-rows 8w..8w+7.
// I-tiles are 32-row (a in [0,24)); J-tiles 16-row with tJ >= 2a.
// Output fragment: lane holds j = lane&15, c = 16*mt + 4*(lane>>4) + reg.
// ---------------------------------------------------------------------------
__global__ __launch_bounds__(256, 3) void pair_kernel(
    const float* __restrict__ h, const float* __restrict__ si, const float* __restrict__ sj,
    const float* __restrict__ ps_b1, const float* __restrict__ ps_w2,
    const float* __restrict__ ps_b2, const unsigned short* __restrict__ wdf,
    float* __restrict__ delta)
{
  int bidx = blockIdx.x;
  int b = bidx / PERB;
  int t = bidx % PERB;
  int a = 0;
  while (t >= NTILES - 2 * a) { t -= NTILES - 2 * a; ++a; }
  int tJ = 2 * a + t;
  const int i0 = a * TI32, j0 = tJ * TILE;

  __shared__ float hI  [TI32][HID_];       // group-broadcast reads
  __shared__ float hJT [HID_][TILE + 1];   // transposed h_J
  __shared__ float SIIb[TI32][SSTR];       // s_i[I] + b1
  __shared__ float SJI_[TI32][SSTR];       // s_j[I]
  __shared__ float SIJb[TILE][SSTR];       // s_i[J] + b1
  __shared__ float SJJ_[TILE][SSTR];       // s_j[J]
  __shared__ float w2s [HID_];

  const int tid  = threadIdx.x;
  const int lane = tid & 63;
  const int w    = tid >> 6;

  {
    const int r  = tid >> 4;        // 0..15
    const int c4 = (tid & 15) * 4;
    const f32x4 b14 = *(const f32x4*)(ps_b1 + c4);
    #pragma unroll
    for (int p = 0; p < 2; ++p) {
      const int rr = r + p * 16;
      const long gi = ((long)b * N_ + i0 + rr) * HID_ + c4;
      *(f32x4*)&hI  [rr][c4] = *(const f32x4*)(h  + gi);
      *(f32x4*)&SIIb[rr][c4] = *(const f32x4*)(si + gi) + b14;
      *(f32x4*)&SJI_[rr][c4] = *(const f32x4*)(sj + gi);
    }
    const long gj = ((long)b * N_ + j0 + r) * HID_ + c4;
    f32x4 vhj = *(const f32x4*)(h + gj);
    #pragma unroll
    for (int q = 0; q < 4; ++q) hJT[c4 + q][r] = vhj[q];
    *(f32x4*)&SIJb[r][c4] = *(const f32x4*)(si + gj) + b14;
    *(f32x4*)&SJJ_[r][c4] = *(const f32x4*)(sj + gj);
    if (tid < 16) *(f32x4*)&w2s[tid * 4] = *(const f32x4*)(ps_w2 + tid * 4);
  }
  const float b2 = ps_b2[0];
  __syncthreads();

  const int g   = lane >> 4;     // 0..3
  const int c16 = lane & 15;     // = j within tile

  // Wd fragments (A operand), prepacked
  short8v wfr[8];
  const short8v* wdp = (const short8v*)wdf;
  #pragma unroll
  for (int q = 0; q < 8; ++q) wfr[q] = wdp[q * 64 + lane];

  // h_J values this lane needs for B-fragment build (j = c16, k = 32s+8g+jj)
  float hJv[2][8];
  #pragma unroll
  for (int s = 0; s < 2; ++s)
    #pragma unroll
    for (int jj = 0; jj < 8; ++jj)
      hJv[s][jj] = hJT[32 * s + 8 * g + jj][c16];

  // m-invariant epilogue operands (hoisted)
  f32x4 sJJ4h[4], sIJ4h[4], w24h[4];
  #pragma unroll
  for (int mt = 0; mt < 4; ++mt) {
    const int cb = 16 * mt + 4 * g;
    sJJ4h[mt] = *(const f32x4*)&SJJ_[c16][cb];
    sIJ4h[mt] = *(const f32x4*)&SIJb[c16][cb];
    w24h[mt]  = *(const f32x4*)&w2s[cb];
  }

  float* drow = delta + (long)b * N_ * N_;

  #pragma unroll
  for (int m = 0; m < 8; ++m) {
    const int iloc = w * 8 + m;
    const int i = i0 + iloc;

    // B-fragments: |h_i - h_j|, col=j=c16, k=32s+8g+jj  (v_cvt_pk_bf16_f32)
    short8v afr[2];
    #pragma unroll
    for (int s = 0; s < 2; ++s) {
      f32x4 ha = *(const f32x4*)&hI[iloc][32 * s + 8 * g];
      f32x4 hb = *(const f32x4*)&hI[iloc][32 * s + 8 * g + 4];
      uint4v uv;
      #pragma unroll
      for (int p = 0; p < 2; ++p) {
        float d0 = fabsf(ha[2*p]   - hJv[s][2*p]);
        float d1 = fabsf(ha[2*p+1] - hJv[s][2*p+1]);
        uv[p] = pack_bf2(d0, d1);
      }
      #pragma unroll
      for (int p = 0; p < 2; ++p) {
        float d0 = fabsf(hb[2*p]   - hJv[s][4 + 2*p]);
        float d1 = fabsf(hb[2*p+1] - hJv[s][4 + 2*p+1]);
        uv[2 + p] = pack_bf2(d0, d1);
      }
      afr[s] = __builtin_bit_cast(short8v, uv);
    }

    f32x4 acc[4];
    #pragma unroll
    for (int mt = 0; mt < 4; ++mt) acc[mt] = (f32x4){0.f, 0.f, 0.f, 0.f};
    #pragma unroll
    for (int s = 0; s < 2; ++s)
      #pragma unroll
      for (int mt = 0; mt < 4; ++mt)
        acc[mt] = __builtin_amdgcn_mfma_f32_16x16x32_bf16(wfr[2 * mt + s], afr[s], acc[mt], 0, 0, 0);

    // epilogue: lane holds j=c16, c = 16mt + 4g + r
    float a1 = 0.f, a2 = 0.f;
    #pragma unroll
    for (int mt = 0; mt < 4; ++mt) {
      const int cb = 16 * mt + 4 * g;
      f32x4 sII4 = *(const f32x4*)&SIIb[iloc][cb];   // broadcast per group
      f32x4 sJI4 = *(const f32x4*)&SJI_[iloc][cb];
      #pragma unroll
      for (int r = 0; r < 4; ++r) {
        float av = acc[mt][r];
        a1 += fmaxf(av + sII4[r] + sJJ4h[mt][r], 0.f) * w24h[mt][r];   // pre(i,j)
        a2 += fmaxf(av + sJI4[r] + sIJ4h[mt][r], 0.f) * w24h[mt][r];   // pre(j,i)
      }
    }
    a1 += __shfl_xor(a1, 16);  a1 += __shfl_xor(a1, 32);
    a2 += __shfl_xor(a2, 16);  a2 += __shfl_xor(a2, 32);

    if (g == 0) {
      const int j = j0 + c16;
      if (i < j) {
        float sym = 0.5f * (ftanh(a1 + b2) + ftanh(a2 + b2));
        drow[(long)i * N_ + j] = sym;
        drow[(long)j * N_ + i] = sym;
      } else if (i == j) {
        drow[(long)i * N_ + i] = 0.f;
      }
    }
  }
}

// ---------------------------------------------------------------------------
// Kernel 3: a_hybrid = relu(a_static + lam*delta) row-normalized, in place.
// ---------------------------------------------------------------------------
__global__ __launch_bounds__(256) void norm_kernel(
    const float* __restrict__ a_static, const float* __restrict__ raw_lambda,
    float* __restrict__ out)
{
  const int row = blockIdx.x;           // b*N + i
  const int i   = row % N_;
  const int tid = threadIdx.x;
  const float lam = 1.f / (1.f + expf(-raw_lambda[0]));

  const float* arow = a_static + (long)i * N_;
  float* drow = out + (long)row * N_;

  float vals[3];
  float s = 0.f;
  #pragma unroll
  for (int r = 0; r < 3; ++r) {
    int j = r * 256 + tid;
    float v = arow[j] + lam * drow[j];
    v = fmaxf(v, 0.f);
    vals[r] = v;
    s += v;
  }
  s = wave_sum64(s);
  __shared__ float ps[4];
  if ((tid & 63) == 0) ps[tid >> 6] = s;
  __syncthreads();
  float tot = ps[0] + ps[1] + ps[2] + ps[3];
  float inv = 1.f / fmaxf(tot, 1e-6f);
  #pragma unroll
  for (int r = 0; r < 3; ++r) {
    int j = r * 256 + tid;
    drow[j] = vals[r] * inv;
  }
  if (row == 0 && tid == 0) out[(long)B_ * N_ * N_] = lam;
}

// ---------------------------------------------------------------------------
extern "C" void kernel_launch(void* const* d_in, const int* in_sizes, int n_in,
                              void* d_out, int out_size, void* d_ws, size_t ws_size,
                              hipStream_t stream) {
  const float* x_hist     = (const float*)d_in[0];
  const float* x_mark     = (const float*)d_in[1];
  const float* a_static   = (const float*)d_in[2];
  const float* te_w1      = (const float*)d_in[3];
  const float* te_b1      = (const float*)d_in[4];
  const float* te_w2      = (const float*)d_in[5];
  const float* te_b2      = (const float*)d_in[6];
  const float* me_w1      = (const float*)d_in[7];
  const float* me_b1      = (const float*)d_in[8];
  const float* me_w2      = (const float*)d_in[9];
  const float* me_b2      = (const float*)d_in[10];
  const float* nf_w       = (const float*)d_in[11];
  const float* nf_b       = (const float*)d_in[12];
  const float* ps_w1      = (const float*)d_in[13];
  const float* ps_b1      = (const float*)d_in[14];
  const float* ps_w2      = (const float*)d_in[15];
  const float* ps_b2      = (const float*)d_in[16];
  const float* raw_lambda = (const float*)d_in[17];

  float* out = (float*)d_out;
  float* h   = (float*)d_ws;                 // B*N*64 f32
  float* si  = h  + (long)B_ * N_ * HID_;
  float* sj  = si + (long)B_ * N_ * HID_;
  unsigned short* wdf = (unsigned short*)(sj + (long)B_ * N_ * HID_);  // 4096 bf16

  feat_kernel<<<B_ * N_ + 8, 64, 0, stream>>>(
      x_hist, x_mark, te_w1, te_b1, te_w2, te_b2,
      me_w1, me_b1, me_w2, me_b2, nf_w, nf_b, ps_w1, h, si, sj, wdf);

  pair_kernel<<<B_ * PERB, 256, 0, stream>>>(
      h, si, sj, ps_b1, ps_w2, ps_b2, wdf, out);

  norm_kernel<<<B_ * N_, 256, 0, stream>>>(a_static, raw_lambda, out);
}